// Round 7
// baseline (543.186 us; speedup 1.0000x reference)
//
#include <hip/hip_runtime.h>

// ---------------------------------------------------------------------------
// DSTGCN fused pipeline, MI355X gfx950.
// k_prep : LN(node+time)->e,eq | x->xT (LDS-tiled) | ne_bf | wpT | bias
// k_attn : flash attention, no-max softmax (LN bounds |logit|<=64),
//          S^T = K.Q^T (P exits MFMA with lane=q), PV A-frags in-register.
//          8 waves/block, 8-way key split (TLP: 6 waves/SIMD — register
//          double-buffering is defeated by the compiler, so latency is
//          hidden with occupancy instead).
// k_hyper: EXACT round-4 version (known good).
// ---------------------------------------------------------------------------

using bf16x8 = __attribute__((ext_vector_type(8))) __bf16;
using f32x4  = __attribute__((ext_vector_type(4))) float;
using f32x16 = __attribute__((ext_vector_type(16))) float;

__device__ __forceinline__ unsigned short f2bf_bits(float f) {
    unsigned int u = __float_as_uint(f);
    u += 0x7fffu + ((u >> 16) & 1u);          // RNE
    return (unsigned short)(u >> 16);
}

__device__ __forceinline__ f32x4 mfma16(bf16x8 a, bf16x8 b, f32x4 c) {
    return __builtin_amdgcn_mfma_f32_16x16x32_bf16(a, b, c, 0, 0, 0);
}
__device__ __forceinline__ f32x16 mfma32(bf16x8 a, bf16x8 b, f32x16 c) {
    return __builtin_amdgcn_mfma_f32_32x32x16_bf16(a, b, c, 0, 0, 0);
}
__device__ __forceinline__ f32x16 zero16() {
    f32x16 z;
    #pragma unroll
    for (int i = 0; i < 16; ++i) z[i] = 0.f;
    return z;
}

// ---------------- k_prep: all preprocessing in one launch ------------------
__global__ __launch_bounds__(256) void k_prep(const float* __restrict__ x,
                                              const float* __restrict__ node_emb,
                                              const float* __restrict__ time_emb,
                                              const float* __restrict__ wp,
                                              const float* __restrict__ bias_pool,
                                              const float* __restrict__ gamma,
                                              const float* __restrict__ beta,
                                              unsigned short* __restrict__ e_bf,
                                              unsigned short* __restrict__ eq_bf,
                                              unsigned short* __restrict__ xT,
                                              unsigned short* __restrict__ ne_bf,
                                              unsigned short* __restrict__ wpT,
                                              float* __restrict__ biasw) {
    __shared__ float tile[64 * 65];
    const int b = blockIdx.x;
    const int t = threadIdx.x;
    if (b < 6144) {                               // ---- LayerNorm ----
        int row  = b * 4 + (t >> 6);              // bt*4096+n
        int lane = t & 63;
        int bt = row >> 12, n = row & 4095;
        float v = node_emb[(n << 6) | lane] + time_emb[(bt << 6) | lane];
        float s = v, s2 = v * v;
        #pragma unroll
        for (int off = 32; off; off >>= 1) {
            s  += __shfl_xor(s,  off);
            s2 += __shfl_xor(s2, off);
        }
        float mu  = s * 0.015625f;
        float var = s2 * 0.015625f - mu * mu;
        float r   = rsqrtf(var + 1e-12f);
        float o   = (v - mu) * r * gamma[lane] + beta[lane];
        e_bf [(row << 6) | lane] = f2bf_bits(o);
        eq_bf[(row << 6) | lane] = f2bf_bits(o * 1.44269504f);
    } else if (b < 6528) {                        // ---- x transpose ----
        int bb = b - 6144;
        int bt = bb >> 6, n0 = (bb & 63) << 6;
        const float* xr = x + ((size_t)((bt << 12) | n0) << 6);
        #pragma unroll
        for (int it = 0; it < 16; ++it) {
            int i = (it << 2) + (t >> 6);
            int d = t & 63;
            tile[i * 65 + d] = xr[(i << 6) + d];  // coalesced 256B rows
        }
        __syncthreads();
        unsigned short* dst = xT + ((size_t)bt << 18) + n0;
        #pragma unroll
        for (int it = 0; it < 16; ++it) {
            int d = (it << 2) + (t >> 6);
            int n = t & 63;
            dst[((size_t)d << 12) + n] = f2bf_bits(tile[n * 65 + d]);
        }
    } else if (b < 7552) {                        // ---- ne_bf ----
        int idx = (b - 6528) * 256 + t;
        ne_bf[idx] = f2bf_bits(node_emb[idx]);
    } else if (b < 7680) {                        // ---- wpT ----
        int ki = b - 7552;
        #pragma unroll
        for (int it = 0; it < 16; ++it) {
            int d = (it << 2) + (t >> 6);
            int o = t & 63;
            tile[d * 65 + o] = wp[(d << 13) + (ki << 6) + o];
        }
        __syncthreads();
        #pragma unroll
        for (int j = 0; j < 16; ++j) {
            int idx = (j << 8) + t;
            int o = idx >> 6, d = idx & 63;
            wpT[(((ki << 6) + o) << 6) + d] = f2bf_bits(tile[d * 65 + o]);
        }
    } else {                                      // ---- bias ----
        for (int idx = t; idx < 384; idx += 256) {
            int bt = idx >> 6, o = idx & 63;
            float bsum = 0.f;
            for (int d = 0; d < 64; ++d)
                bsum += time_emb[(bt << 6) + d] * bias_pool[(d << 6) + o];
            biasw[idx] = bsum;
        }
    }
}

// ---------------- k_attn: 8-wave barrier-free flash attention --------------
// Block = 8 waves (512 thr), 32 q rows; wave w owns keys [w*512, w*512+512).
__global__ __launch_bounds__(512, 6) void k_attn(const unsigned short* __restrict__ e_bf,
                                                 const unsigned short* __restrict__ eq_bf,
                                                 const unsigned short* __restrict__ xT,
                                                 float* __restrict__ xg2) {
    __shared__ __align__(16) float Obuf[4][32 * 68];   // 34.8 KB merge buffers
    __shared__ float l_s[8][32];
    const int tid  = threadIdx.x;
    const int w    = tid >> 6;
    const int lane = tid & 63;
    const int l32  = lane & 31;
    const int h    = lane >> 5;

    // XCD-aware swizzle (bijective over 768)
    const int bid   = blockIdx.x;
    const int x8    = bid & 7;
    const int g     = (bid >> 3) & 31;
    const int r3    = bid >> 8;
    const int combo = x8 * 3 + r3;               // 0..23
    const int bt    = combo >> 2;
    const int qbase = ((((combo & 3) << 5) + g) << 5);

    const unsigned short* eb  = e_bf  + ((size_t)bt << 18);
    const unsigned short* eqb = eq_bf + ((size_t)bt << 18);
    const unsigned short* xb  = xT    + ((size_t)bt << 18);

    // Q as B-operand (pre-scaled by log2e): lane n=l32=q, k=h*8+j, d=c*16+k
    bf16x8 qf[4];
    #pragma unroll
    for (int c = 0; c < 4; ++c)
        qf[c] = *(const bf16x8*)(eqb + ((qbase + l32) << 6) + (c << 4) + (h << 3));

    f32x16 O0 = zero16(), O1 = zero16();
    float ls = 0.f;

    const int kstart = w << 9;                   // 512 keys per wave
    const unsigned short* kr = eb + ((size_t)(kstart + l32) << 6) + (h << 3);
    const unsigned short* vr = xb + ((size_t)l32 << 12) + kstart + (h << 3);

    bf16x8 kA0, kA1, kA2, kA3, vA0, vA1, vA2, vA3;
    bf16x8 kB0, kB1, kB2, kB3, vB0, vB1, vB2, vB3;

#define LOAD_GRP(gi, K0, K1, K2, K3, V0, V1, V2, V3)                    \
    {                                                                   \
        const unsigned short* kp = kr + (gi) * 2048;                    \
        const unsigned short* vp = vr + ((gi) << 5);                    \
        K0 = *(const bf16x8*)(kp);                                      \
        K1 = *(const bf16x8*)(kp + 16);                                 \
        K2 = *(const bf16x8*)(kp + 32);                                 \
        K3 = *(const bf16x8*)(kp + 48);                                 \
        V0 = *(const bf16x8*)(vp);                                      \
        V1 = *(const bf16x8*)(vp + (32 << 12));                         \
        V2 = *(const bf16x8*)(vp + 16);                                 \
        V3 = *(const bf16x8*)(vp + 16 + (32 << 12));                    \
    }

#define COMPUTE_GRP(K0, K1, K2, K3, V0, V1, V2, V3)                     \
    {                                                                   \
        f32x16 S = zero16();                                            \
        S = mfma32(K0, qf[0], S);                                       \
        S = mfma32(K1, qf[1], S);                                       \
        S = mfma32(K2, qf[2], S);                                       \
        S = mfma32(K3, qf[3], S);                                       \
        float p[16];                                                    \
        _Pragma("unroll")                                               \
        for (int r = 0; r < 16; ++r) { p[r] = exp2f(S[r]); ls += p[r]; }\
        float r0[4], r1[4];                                             \
        _Pragma("unroll")                                               \
        for (int j = 0; j < 4; ++j) {                                   \
            r0[j] = __shfl_xor(h ? p[j]     : p[4 + j],  32);           \
            r1[j] = __shfl_xor(h ? p[8 + j] : p[12 + j], 32);           \
        }                                                               \
        bf16x8 pf0, pf1;                                                \
        _Pragma("unroll")                                               \
        for (int j = 0; j < 4; ++j) {                                   \
            pf0[j]     = (__bf16)(h ? r0[j]     : p[j]);                \
            pf0[4 + j] = (__bf16)(h ? p[4 + j]  : r0[j]);               \
            pf1[j]     = (__bf16)(h ? r1[j]     : p[8 + j]);            \
            pf1[4 + j] = (__bf16)(h ? p[12 + j] : r1[j]);               \
        }                                                               \
        O0 = mfma32(pf0, V0, O0);                                       \
        O1 = mfma32(pf0, V1, O1);                                       \
        O0 = mfma32(pf1, V2, O0);                                       \
        O1 = mfma32(pf1, V3, O1);                                       \
    }

    LOAD_GRP(0, kA0, kA1, kA2, kA3, vA0, vA1, vA2, vA3);
    for (int gi = 0; gi < 14; gi += 2) {
        LOAD_GRP(gi + 1, kB0, kB1, kB2, kB3, vB0, vB1, vB2, vB3);
        COMPUTE_GRP(kA0, kA1, kA2, kA3, vA0, vA1, vA2, vA3);
        LOAD_GRP(gi + 2, kA0, kA1, kA2, kA3, vA0, vA1, vA2, vA3);
        COMPUTE_GRP(kB0, kB1, kB2, kB3, vB0, vB1, vB2, vB3);
    }
    LOAD_GRP(15, kB0, kB1, kB2, kB3, vB0, vB1, vB2, vB3);
    COMPUTE_GRP(kA0, kA1, kA2, kA3, vA0, vA1, vA2, vA3);
    COMPUTE_GRP(kB0, kB1, kB2, kB3, vB0, vB1, vB2, vB3);
#undef LOAD_GRP
#undef COMPUTE_GRP

    // ---- merge: l across h, then O across 8 waves via 4 LDS buffers ----
    float lsum2 = ls + __shfl_xor(ls, 32);
    if (h == 0) l_s[w][l32] = lsum2;
    float* buf = Obuf[w & 3];
    if (w < 4) {
        #pragma unroll
        for (int r = 0; r < 16; ++r) {
            int qrow = (r & 3) + ((r >> 2) << 3) + (h << 2);
            buf[qrow * 68 + l32]      = O0[r];
            buf[qrow * 68 + 32 + l32] = O1[r];
        }
    }
    __syncthreads();
    if (w >= 4) {
        #pragma unroll
        for (int r = 0; r < 16; ++r) {
            int qrow = (r & 3) + ((r >> 2) << 3) + (h << 2);
            buf[qrow * 68 + l32]      += O0[r];
            buf[qrow * 68 + 32 + l32] += O1[r];
        }
    }
    __syncthreads();
    {
        int q  = tid >> 4;                 // 0..31
        int d0 = (tid & 15) << 2;          // 0..60
        float lsum = 0.f;
        #pragma unroll
        for (int ww = 0; ww < 8; ++ww) lsum += l_s[ww][q];
        float inv = 1.f / lsum;
        float acc[4];
        #pragma unroll
        for (int i = 0; i < 4; ++i) acc[i] = 0.f;
        #pragma unroll
        for (int bb = 0; bb < 4; ++bb) {
            const float* src = Obuf[bb] + q * 68 + d0;
            #pragma unroll
            for (int i = 0; i < 4; ++i) acc[i] += src[i];
        }
        float* dst = xg2 + (((size_t)(bt << 12) + qbase + q) << 6) + d0;
        #pragma unroll
        for (int i = 0; i < 4; ++i) dst[i] = acc[i] * inv;
    }
}

// ---------------- k_hyper: fused hypernetwork contraction (round-4) --------
__global__ __launch_bounds__(256, 2) void k_hyper(const float* __restrict__ x,
                                                  const float* __restrict__ xg2,
                                                  const unsigned short* __restrict__ ne_bf,
                                                  const unsigned short* __restrict__ wpT,
                                                  const float* __restrict__ bias_ws,
                                                  float* __restrict__ out) {
    __shared__ float smem[13056];          // 52.2 KB: xg (4x3104) then red (4x3264)
    const int t    = threadIdx.x;
    const int w    = t >> 6;
    const int lane = t & 63;
    const int l16  = lane & 15;
    const int quad = lane >> 4;
    const int n0   = (blockIdx.x >> 1) << 4;
    const int oh   = blockIdx.x & 1;       // o-half

    float* xg_s = smem + w * 3104;
    const float* src = (w < 2) ? x : xg2;
    const int i0 = (w & 1) << 5;
    for (int it = 0; it < 48; ++it) {
        int j  = (it << 6) + lane;         // 0..3071
        int kk = j & 31;
        int btnl = j >> 5;                 // 0..95
        int bt = btnl % 6;
        int nl = btnl / 6;
        xg_s[kk * 97 + btnl] =
            src[(((size_t)(bt << 12) + n0 + nl) << 6) + i0 + kk];
    }
    __syncthreads();

    const unsigned short* nb = ne_bf + ((n0 + l16) << 6) + (quad << 3);
    bf16x8 a0 = *(const bf16x8*)(nb);
    bf16x8 a1 = *(const bf16x8*)(nb + 32);

    float oac[2][4][6];
    #pragma unroll
    for (int oc = 0; oc < 2; ++oc)
        #pragma unroll
        for (int r = 0; r < 4; ++r)
            #pragma unroll
            for (int bt = 0; bt < 6; ++bt) oac[oc][r][bt] = 0.f;

    const int ki_base = w << 5;
    #pragma unroll 2
    for (int kk = 0; kk < 32; ++kk) {
        const int ki = ki_base + kk;
        float g[4][6];
        #pragma unroll
        for (int r = 0; r < 4; ++r) {
            const float* gp = xg_s + kk * 97 + ((quad << 2) + r) * 6;
            #pragma unroll
            for (int bt = 0; bt < 6; ++bt) g[r][bt] = gp[bt];
        }
        #pragma unroll
        for (int oc = 0; oc < 2; ++oc) {
            const unsigned short* bp =
                wpT + (((ki << 6) + ((oh * 2 + oc) << 4) + l16) << 6) + (quad << 3);
            bf16x8 b0 = *(const bf16x8*)(bp);
            bf16x8 b1 = *(const bf16x8*)(bp + 32);
            f32x4 wf = mfma16(a0, b0, f32x4{0.f, 0.f, 0.f, 0.f});
            wf = mfma16(a1, b1, wf);
            #pragma unroll
            for (int r = 0; r < 4; ++r)
                #pragma unroll
                for (int bt = 0; bt < 6; ++bt)
                    oac[oc][r][bt] += wf[r] * g[r][bt];
        }
    }

    __syncthreads();                        // xg_s dead; smem becomes red
    #pragma unroll
    for (int oc = 0; oc < 2; ++oc)
        #pragma unroll
        for (int r = 0; r < 4; ++r)
            #pragma unroll
            for (int bt = 0; bt < 6; ++bt)
                smem[w * 3264 + ((quad << 2) + r) * 204 + bt * 34 + (oc << 4) + l16]
                    = oac[oc][r][bt];
    __syncthreads();
    #pragma unroll
    for (int rr = 0; rr < 4; ++rr) {
        int nl = (w << 2) + rr;
        #pragma unroll
        for (int bp2 = 0; bp2 < 3; ++bp2) {
            int bt = bp2 * 2 + (lane >> 5);
            int ol = lane & 31;
            int o  = (oh << 5) + ol;
            int a  = nl * 204 + bt * 34 + ol;
            float v = smem[a] + smem[a + 3264] + smem[a + 6528] + smem[a + 9792]
                    + bias_ws[(bt << 6) + o];
            out[(((size_t)(bt << 12) + n0 + nl) << 6) + o] = v;
        }
    }
}

// ---------------------------------------------------------------------------
extern "C" void kernel_launch(void* const* d_in, const int* in_sizes, int n_in,
                              void* d_out, int out_size, void* d_ws, size_t ws_size,
                              hipStream_t stream) {
    const float* x         = (const float*)d_in[0];
    const float* node_emb  = (const float*)d_in[1];
    const float* time_emb  = (const float*)d_in[2];
    const float* wp        = (const float*)d_in[3];
    const float* bias_pool = (const float*)d_in[4];
    const float* gamma     = (const float*)d_in[5];
    const float* beta      = (const float*)d_in[6];
    float* out = (float*)d_out;

    char* wsb = (char*)d_ws;
    unsigned short* e_bf  = (unsigned short*)(wsb);                  // 3 MB
    unsigned short* eq_bf = (unsigned short*)(wsb + 3145728);        // 3 MB
    unsigned short* xT    = (unsigned short*)(wsb + 6291456);        // 3 MB
    float*          xg2   = (float*)         (wsb + 9437184);        // 6.3 MB
    unsigned short* wpT   = (unsigned short*)(wsb + 15728640);       // 1 MB
    unsigned short* ne_bf = (unsigned short*)(wsb + 16777216);       // 0.5 MB
    float*          biasw = (float*)         (wsb + 17301504);       // 1.5 KB

    k_prep<<<7681, 256, 0, stream>>>(x, node_emb, time_emb, wp, bias_pool,
                                     gamma, beta, e_bf, eq_bf, xT, ne_bf, wpT, biasw);
    k_attn<<<768, 512, 0, stream>>>(e_bf, eq_bf, xT, xg2);
    k_hyper<<<512, 256, 0, stream>>>(x, xg2, ne_bf, wpT, biasw, out);
}

// Round 8
// 217.187 us; speedup vs baseline: 2.5010x; 2.5010x over previous
//
#include <hip/hip_runtime.h>

// ---------------------------------------------------------------------------
// DSTGCN fused pipeline, MI355X gfx950.
// k_prep : LN(node+time)->e | x->xT (LDS-tiled) | ne_bf | wpT | bias
// k_attn : flash attention, no-max softmax (LN bounds |logit|<=64).
//          S^T = K.Q^T, PV A-frags in-register. 256-thr blocks (round-6
//          known-good core); keys split across 2 blocks (grid 1536 = 6
//          blocks/CU) writing unnormalized partial (O,l); merge+normalize
//          folded into k_hyper's staging. [round-7 lesson: 512-thr +
//          launch_bounds(512,6) spilled accumulators to scratch]
// k_hyper: out = x*W0 + xg2*W1 + bias; main loop byte-identical to the
//          known-good round-4 version; staging now merges the 2 partials.
// ---------------------------------------------------------------------------

using bf16x8 = __attribute__((ext_vector_type(8))) __bf16;
using f32x4  = __attribute__((ext_vector_type(4))) float;
using f32x16 = __attribute__((ext_vector_type(16))) float;

__device__ __forceinline__ unsigned short f2bf_bits(float f) {
    unsigned int u = __float_as_uint(f);
    u += 0x7fffu + ((u >> 16) & 1u);          // RNE
    return (unsigned short)(u >> 16);
}

__device__ __forceinline__ f32x4 mfma16(bf16x8 a, bf16x8 b, f32x4 c) {
    return __builtin_amdgcn_mfma_f32_16x16x32_bf16(a, b, c, 0, 0, 0);
}
__device__ __forceinline__ f32x16 mfma32(bf16x8 a, bf16x8 b, f32x16 c) {
    return __builtin_amdgcn_mfma_f32_32x32x16_bf16(a, b, c, 0, 0, 0);
}
__device__ __forceinline__ f32x16 zero16() {
    f32x16 z;
    #pragma unroll
    for (int i = 0; i < 16; ++i) z[i] = 0.f;
    return z;
}

// ---------------- k_prep: all preprocessing in one launch ------------------
__global__ __launch_bounds__(256) void k_prep(const float* __restrict__ x,
                                              const float* __restrict__ node_emb,
                                              const float* __restrict__ time_emb,
                                              const float* __restrict__ wp,
                                              const float* __restrict__ bias_pool,
                                              const float* __restrict__ gamma,
                                              const float* __restrict__ beta,
                                              unsigned short* __restrict__ e_bf,
                                              unsigned short* __restrict__ xT,
                                              unsigned short* __restrict__ ne_bf,
                                              unsigned short* __restrict__ wpT,
                                              float* __restrict__ biasw) {
    __shared__ float tile[64 * 65];
    const int b = blockIdx.x;
    const int t = threadIdx.x;
    if (b < 6144) {                               // ---- LayerNorm ----
        int row  = b * 4 + (t >> 6);              // bt*4096+n
        int lane = t & 63;
        int bt = row >> 12, n = row & 4095;
        float v = node_emb[(n << 6) | lane] + time_emb[(bt << 6) | lane];
        float s = v, s2 = v * v;
        #pragma unroll
        for (int off = 32; off; off >>= 1) {
            s  += __shfl_xor(s,  off);
            s2 += __shfl_xor(s2, off);
        }
        float mu  = s * 0.015625f;
        float var = s2 * 0.015625f - mu * mu;
        float r   = rsqrtf(var + 1e-12f);
        float o   = (v - mu) * r * gamma[lane] + beta[lane];
        e_bf[(row << 6) | lane] = f2bf_bits(o);
    } else if (b < 6528) {                        // ---- x transpose ----
        int bb = b - 6144;
        int bt = bb >> 6, n0 = (bb & 63) << 6;
        const float* xr = x + ((size_t)((bt << 12) | n0) << 6);
        #pragma unroll
        for (int it = 0; it < 16; ++it) {
            int i = (it << 2) + (t >> 6);
            int d = t & 63;
            tile[i * 65 + d] = xr[(i << 6) + d];  // coalesced 256B rows
        }
        __syncthreads();
        unsigned short* dst = xT + ((size_t)bt << 18) + n0;
        #pragma unroll
        for (int it = 0; it < 16; ++it) {
            int d = (it << 2) + (t >> 6);
            int n = t & 63;
            dst[((size_t)d << 12) + n] = f2bf_bits(tile[n * 65 + d]);
        }
    } else if (b < 7552) {                        // ---- ne_bf ----
        int idx = (b - 6528) * 256 + t;
        ne_bf[idx] = f2bf_bits(node_emb[idx]);
    } else if (b < 7680) {                        // ---- wpT ----
        int ki = b - 7552;
        #pragma unroll
        for (int it = 0; it < 16; ++it) {
            int d = (it << 2) + (t >> 6);
            int o = t & 63;
            tile[d * 65 + o] = wp[(d << 13) + (ki << 6) + o];
        }
        __syncthreads();
        #pragma unroll
        for (int j = 0; j < 16; ++j) {
            int idx = (j << 8) + t;
            int o = idx >> 6, d = idx & 63;
            wpT[(((ki << 6) + o) << 6) + d] = f2bf_bits(tile[d * 65 + o]);
        }
    } else {                                      // ---- bias ----
        for (int idx = t; idx < 384; idx += 256) {
            int bt = idx >> 6, o = idx & 63;
            float bsum = 0.f;
            for (int d = 0; d < 64; ++d)
                bsum += time_emb[(bt << 6) + d] * bias_pool[(d << 6) + o];
            biasw[idx] = bsum;
        }
    }
}

// ---------------- k_attn: half-key flash attention -------------------------
// Block = 4 waves, 32 q rows, one key-half (2048 keys); wave w owns keys
// [half*2048 + w*512, +512). Writes unnormalized partial O + partial l.
__global__ __launch_bounds__(256, 3) void k_attn(const unsigned short* __restrict__ e_bf,
                                                 const unsigned short* __restrict__ xT,
                                                 float* __restrict__ P0,
                                                 float* __restrict__ P1,
                                                 float* __restrict__ L0,
                                                 float* __restrict__ L1) {
    __shared__ __align__(16) float Obuf[2][32 * 68];   // 17.4 KB merge buffers
    __shared__ float l_s[4][32];
    const int tid  = threadIdx.x;
    const int w    = tid >> 6;
    const int lane = tid & 63;
    const int l32  = lane & 31;
    const int h    = lane >> 5;

    // bid = inner*2 + half; round-6 XCD swizzle on inner (bijective over 768)
    const int bid   = blockIdx.x;
    const int half  = bid & 1;
    const int inner = bid >> 1;
    const int x8    = inner & 7;
    const int g     = (inner >> 3) & 31;
    const int r3    = inner >> 8;
    const int combo = x8 * 3 + r3;               // 0..23
    const int bt    = combo >> 2;
    const int qbase = ((((combo & 3) << 5) + g) << 5);

    const unsigned short* eb = e_bf + ((size_t)bt << 18);
    const unsigned short* xb = xT   + ((size_t)bt << 18);
    float* Pout = half ? P1 : P0;
    float* Lout = half ? L1 : L0;

    // Q as B-operand: lane n=l32=q, k=h*8+j, d=c*16+k; scale by log2e here
    bf16x8 qf[4];
    #pragma unroll
    for (int c = 0; c < 4; ++c) {
        bf16x8 q = *(const bf16x8*)(eb + ((qbase + l32) << 6) + (c << 4) + (h << 3));
        #pragma unroll
        for (int j = 0; j < 8; ++j) q[j] = (__bf16)((float)q[j] * 1.44269504f);
        qf[c] = q;
    }

    f32x16 O0 = zero16(), O1 = zero16();
    float ls = 0.f;

    const int kstart = (half << 11) + (w << 9);  // 512 keys per wave
    const unsigned short* kr = eb + ((size_t)(kstart + l32) << 6) + (h << 3);
    const unsigned short* vr = xb + ((size_t)l32 << 12) + kstart + (h << 3);

    bf16x8 kA0, kA1, kA2, kA3, vA0, vA1, vA2, vA3;
    bf16x8 kB0, kB1, kB2, kB3, vB0, vB1, vB2, vB3;

#define LOAD_GRP(gi, K0, K1, K2, K3, V0, V1, V2, V3)                    \
    {                                                                   \
        const unsigned short* kp = kr + (gi) * 2048;                    \
        const unsigned short* vp = vr + ((gi) << 5);                    \
        K0 = *(const bf16x8*)(kp);                                      \
        K1 = *(const bf16x8*)(kp + 16);                                 \
        K2 = *(const bf16x8*)(kp + 32);                                 \
        K3 = *(const bf16x8*)(kp + 48);                                 \
        V0 = *(const bf16x8*)(vp);                                      \
        V1 = *(const bf16x8*)(vp + (32 << 12));                         \
        V2 = *(const bf16x8*)(vp + 16);                                 \
        V3 = *(const bf16x8*)(vp + 16 + (32 << 12));                    \
    }

#define COMPUTE_GRP(K0, K1, K2, K3, V0, V1, V2, V3)                     \
    {                                                                   \
        f32x16 S = zero16();                                            \
        S = mfma32(K0, qf[0], S);                                       \
        S = mfma32(K1, qf[1], S);                                       \
        S = mfma32(K2, qf[2], S);                                       \
        S = mfma32(K3, qf[3], S);                                       \
        float p[16];                                                    \
        _Pragma("unroll")                                               \
        for (int r = 0; r < 16; ++r) { p[r] = exp2f(S[r]); ls += p[r]; }\
        float r0[4], r1[4];                                             \
        _Pragma("unroll")                                               \
        for (int j = 0; j < 4; ++j) {                                   \
            r0[j] = __shfl_xor(h ? p[j]     : p[4 + j],  32);           \
            r1[j] = __shfl_xor(h ? p[8 + j] : p[12 + j], 32);           \
        }                                                               \
        bf16x8 pf0, pf1;                                                \
        _Pragma("unroll")                                               \
        for (int j = 0; j < 4; ++j) {                                   \
            pf0[j]     = (__bf16)(h ? r0[j]     : p[j]);                \
            pf0[4 + j] = (__bf16)(h ? p[4 + j]  : r0[j]);               \
            pf1[j]     = (__bf16)(h ? r1[j]     : p[8 + j]);            \
            pf1[4 + j] = (__bf16)(h ? p[12 + j] : r1[j]);               \
        }                                                               \
        O0 = mfma32(pf0, V0, O0);                                       \
        O1 = mfma32(pf0, V1, O1);                                       \
        O0 = mfma32(pf1, V2, O0);                                       \
        O1 = mfma32(pf1, V3, O1);                                       \
    }

    LOAD_GRP(0, kA0, kA1, kA2, kA3, vA0, vA1, vA2, vA3);
    for (int gi = 0; gi < 14; gi += 2) {
        LOAD_GRP(gi + 1, kB0, kB1, kB2, kB3, vB0, vB1, vB2, vB3);
        COMPUTE_GRP(kA0, kA1, kA2, kA3, vA0, vA1, vA2, vA3);
        LOAD_GRP(gi + 2, kA0, kA1, kA2, kA3, vA0, vA1, vA2, vA3);
        COMPUTE_GRP(kB0, kB1, kB2, kB3, vB0, vB1, vB2, vB3);
    }
    LOAD_GRP(15, kB0, kB1, kB2, kB3, vB0, vB1, vB2, vB3);
    COMPUTE_GRP(kA0, kA1, kA2, kA3, vA0, vA1, vA2, vA3);
    COMPUTE_GRP(kB0, kB1, kB2, kB3, vB0, vB1, vB2, vB3);
#undef LOAD_GRP
#undef COMPUTE_GRP

    // ---- merge: l across h, then O across 4 waves via 2 LDS buffers ----
    float lsum2 = ls + __shfl_xor(ls, 32);
    if (h == 0) l_s[w][l32] = lsum2;
    float* buf = Obuf[w & 1];
    if (w < 2) {
        #pragma unroll
        for (int r = 0; r < 16; ++r) {
            int qrow = (r & 3) + ((r >> 2) << 3) + (h << 2);
            buf[qrow * 68 + l32]      = O0[r];
            buf[qrow * 68 + 32 + l32] = O1[r];
        }
    }
    __syncthreads();
    if (w >= 2) {
        #pragma unroll
        for (int r = 0; r < 16; ++r) {
            int qrow = (r & 3) + ((r >> 2) << 3) + (h << 2);
            buf[qrow * 68 + l32]      += O0[r];
            buf[qrow * 68 + 32 + l32] += O1[r];
        }
    }
    __syncthreads();
    {
        int q  = tid >> 3;
        int d0 = (tid & 7) << 3;
        const float* b0 = Obuf[0] + q * 68 + d0;
        const float* b1 = Obuf[1] + q * 68 + d0;
        float* dst = Pout + (((size_t)(bt << 12) + qbase + q) << 6) + d0;
        #pragma unroll
        for (int i = 0; i < 8; ++i) dst[i] = b0[i] + b1[i];
        if ((tid & 7) == 0)
            Lout[(bt << 12) + qbase + q] =
                l_s[0][q] + l_s[1][q] + l_s[2][q] + l_s[3][q];
    }
}

// ---------------- k_hyper: fused hypernetwork contraction ------------------
// Main loop byte-identical to round-4 (known good); staging merges the two
// attention partials: xg2 = (P0+P1) * 1/(L0+L1).
__global__ __launch_bounds__(256, 2) void k_hyper(const float* __restrict__ x,
                                                  const float* __restrict__ P0,
                                                  const float* __restrict__ P1,
                                                  const float* __restrict__ L0,
                                                  const float* __restrict__ L1,
                                                  const unsigned short* __restrict__ ne_bf,
                                                  const unsigned short* __restrict__ wpT,
                                                  const float* __restrict__ bias_ws,
                                                  float* __restrict__ out) {
    __shared__ float smem[13056];          // 52.2 KB: xg (4x3104) then red (4x3264)
    __shared__ float invl_s[96];
    const int t    = threadIdx.x;
    const int w    = t >> 6;
    const int lane = t & 63;
    const int l16  = lane & 15;
    const int quad = lane >> 4;
    const int n0   = (blockIdx.x >> 1) << 4;
    const int oh   = blockIdx.x & 1;       // o-half

    if (t < 96) {
        int bt = t % 6, nl = t / 6;
        int idx = (bt << 12) + n0 + nl;
        invl_s[t] = 1.f / (L0[idx] + L1[idx]);
    }
    __syncthreads();

    float* xg_s = smem + w * 3104;
    const int i0 = (w & 1) << 5;
    for (int it = 0; it < 48; ++it) {
        int j  = (it << 6) + lane;         // 0..3071
        int kk = j & 31;
        int btnl = j >> 5;                 // 0..95
        int bt = btnl % 6;
        int nl = btnl / 6;
        size_t idx = (((size_t)(bt << 12) + n0 + nl) << 6) + i0 + kk;
        float v;
        if (w < 2) v = x[idx];
        else       v = (P0[idx] + P1[idx]) * invl_s[btnl];
        xg_s[kk * 97 + btnl] = v;
    }
    __syncthreads();

    const unsigned short* nb = ne_bf + ((n0 + l16) << 6) + (quad << 3);
    bf16x8 a0 = *(const bf16x8*)(nb);
    bf16x8 a1 = *(const bf16x8*)(nb + 32);

    float oac[2][4][6];
    #pragma unroll
    for (int oc = 0; oc < 2; ++oc)
        #pragma unroll
        for (int r = 0; r < 4; ++r)
            #pragma unroll
            for (int bt = 0; bt < 6; ++bt) oac[oc][r][bt] = 0.f;

    const int ki_base = w << 5;
    #pragma unroll 2
    for (int kk = 0; kk < 32; ++kk) {
        const int ki = ki_base + kk;
        float g[4][6];
        #pragma unroll
        for (int r = 0; r < 4; ++r) {
            const float* gp = xg_s + kk * 97 + ((quad << 2) + r) * 6;
            #pragma unroll
            for (int bt = 0; bt < 6; ++bt) g[r][bt] = gp[bt];
        }
        #pragma unroll
        for (int oc = 0; oc < 2; ++oc) {
            const unsigned short* bp =
                wpT + (((ki << 6) + ((oh * 2 + oc) << 4) + l16) << 6) + (quad << 3);
            bf16x8 b0 = *(const bf16x8*)(bp);
            bf16x8 b1 = *(const bf16x8*)(bp + 32);
            f32x4 wf = mfma16(a0, b0, f32x4{0.f, 0.f, 0.f, 0.f});
            wf = mfma16(a1, b1, wf);
            #pragma unroll
            for (int r = 0; r < 4; ++r)
                #pragma unroll
                for (int bt = 0; bt < 6; ++bt)
                    oac[oc][r][bt] += wf[r] * g[r][bt];
        }
    }

    __syncthreads();                        // xg_s dead; smem becomes red
    #pragma unroll
    for (int oc = 0; oc < 2; ++oc)
        #pragma unroll
        for (int r = 0; r < 4; ++r)
            #pragma unroll
            for (int bt = 0; bt < 6; ++bt)
                smem[w * 3264 + ((quad << 2) + r) * 204 + bt * 34 + (oc << 4) + l16]
                    = oac[oc][r][bt];
    __syncthreads();
    #pragma unroll
    for (int rr = 0; rr < 4; ++rr) {
        int nl = (w << 2) + rr;
        #pragma unroll
        for (int bp2 = 0; bp2 < 3; ++bp2) {
            int bt = bp2 * 2 + (lane >> 5);
            int ol = lane & 31;
            int o  = (oh << 5) + ol;
            int a  = nl * 204 + bt * 34 + ol;
            float v = smem[a] + smem[a + 3264] + smem[a + 6528] + smem[a + 9792]
                    + bias_ws[(bt << 6) + o];
            out[(((size_t)(bt << 12) + n0 + nl) << 6) + o] = v;
        }
    }
}

// ---------------------------------------------------------------------------
extern "C" void kernel_launch(void* const* d_in, const int* in_sizes, int n_in,
                              void* d_out, int out_size, void* d_ws, size_t ws_size,
                              hipStream_t stream) {
    const float* x         = (const float*)d_in[0];
    const float* node_emb  = (const float*)d_in[1];
    const float* time_emb  = (const float*)d_in[2];
    const float* wp        = (const float*)d_in[3];
    const float* bias_pool = (const float*)d_in[4];
    const float* gamma     = (const float*)d_in[5];
    const float* beta      = (const float*)d_in[6];
    float* out = (float*)d_out;

    char* wsb = (char*)d_ws;
    unsigned short* e_bf  = (unsigned short*)(wsb);                  // 3 MB
    unsigned short* xT    = (unsigned short*)(wsb + 3145728);        // 3 MB
    float*          P0    = (float*)         (wsb + 6291456);        // 6.3 MB
    float*          P1    = (float*)         (wsb + 12582912);       // 6.3 MB
    unsigned short* wpT   = (unsigned short*)(wsb + 18874368);       // 1 MB
    unsigned short* ne_bf = (unsigned short*)(wsb + 19922944);       // 0.5 MB
    float*          biasw = (float*)         (wsb + 20447232);       // 1.5 KB
    float*          L0    = (float*)         (wsb + 20448768);       // 96 KB
    float*          L1    = (float*)         (wsb + 20547072);       // 96 KB

    k_prep<<<7681, 256, 0, stream>>>(x, node_emb, time_emb, wp, bias_pool,
                                     gamma, beta, e_bf, xT, ne_bf, wpT, biasw);
    k_attn<<<1536, 256, 0, stream>>>(e_bf, xT, P0, P1, L0, L1);
    k_hyper<<<512, 256, 0, stream>>>(x, P0, P1, L0, L1, ne_bf, wpT, biasw, out);
}

// Round 9
// 172.147 us; speedup vs baseline: 3.1554x; 1.2616x over previous
//
#include <hip/hip_runtime.h>

// ---------------------------------------------------------------------------
// DSTGCN fused pipeline, MI355X gfx950.
// Round 9: MFMA-fragment-friendly workspace layouts so every K/Q/V fragment
// load is lane-contiguous (1KB/wave-instr, 8 cache lines) instead of
// line-divergent (32-64 lines) — the round-8 counters showed a fixed ~60us
// limit independent of occupancy/barriers = L1/TA address throughput.
//   eT[row>>5][d>>4][(d>>3)&1][row&31][d&7]   (K and Q A/B-frags)
//   vT[key>>3][d][key&7]                      (V B-frags)
// Structure (grids, waves, math) byte-identical to round 8. k_hyper untouched.
// ---------------------------------------------------------------------------

using bf16x8 = __attribute__((ext_vector_type(8))) __bf16;
using f32x4  = __attribute__((ext_vector_type(4))) float;
using f32x16 = __attribute__((ext_vector_type(16))) float;

__device__ __forceinline__ unsigned short f2bf_bits(float f) {
    unsigned int u = __float_as_uint(f);
    u += 0x7fffu + ((u >> 16) & 1u);          // RNE
    return (unsigned short)(u >> 16);
}

__device__ __forceinline__ f32x4 mfma16(bf16x8 a, bf16x8 b, f32x4 c) {
    return __builtin_amdgcn_mfma_f32_16x16x32_bf16(a, b, c, 0, 0, 0);
}
__device__ __forceinline__ f32x16 mfma32(bf16x8 a, bf16x8 b, f32x16 c) {
    return __builtin_amdgcn_mfma_f32_32x32x16_bf16(a, b, c, 0, 0, 0);
}
__device__ __forceinline__ f32x16 zero16() {
    f32x16 z;
    #pragma unroll
    for (int i = 0; i < 16; ++i) z[i] = 0.f;
    return z;
}

// ---------------- k_prep: all preprocessing in one launch ------------------
__global__ __launch_bounds__(256) void k_prep(const float* __restrict__ x,
                                              const float* __restrict__ node_emb,
                                              const float* __restrict__ time_emb,
                                              const float* __restrict__ wp,
                                              const float* __restrict__ bias_pool,
                                              const float* __restrict__ gamma,
                                              const float* __restrict__ beta,
                                              unsigned short* __restrict__ eT,
                                              unsigned short* __restrict__ vT,
                                              unsigned short* __restrict__ ne_bf,
                                              unsigned short* __restrict__ wpT,
                                              float* __restrict__ biasw) {
    __shared__ float tile[64 * 65];
    const int b = blockIdx.x;
    const int t = threadIdx.x;
    if (b < 6144) {                               // ---- LayerNorm -> eT ----
        int rowf = b * 4 + (t >> 6);              // bt*4096+n
        int d    = t & 63;
        int bt = rowf >> 12, row = rowf & 4095;
        float v = node_emb[(row << 6) | d] + time_emb[(bt << 6) | d];
        float s = v, s2 = v * v;
        #pragma unroll
        for (int off = 32; off; off >>= 1) {
            s  += __shfl_xor(s,  off);
            s2 += __shfl_xor(s2, off);
        }
        float mu  = s * 0.015625f;
        float var = s2 * 0.015625f - mu * mu;
        float r   = rsqrtf(var + 1e-12f);
        float o   = (v - mu) * r * gamma[d] + beta[d];
        // eT idx: (row>>5)*2048 + (d>>4)*512 + ((d>>3)&1)*256 + (row&31)*8 + (d&7)
        size_t idx = (size_t)bt * 262144 + ((row >> 5) << 11) + ((d >> 4) << 9)
                   + (((d >> 3) & 1) << 8) + ((row & 31) << 3) + (d & 7);
        eT[idx] = f2bf_bits(o);
    } else if (b < 6528) {                        // ---- x -> vT ----
        int bb = b - 6144;
        int bt = bb >> 6, n0 = (bb & 63) << 6;
        const float* xr = x + ((size_t)((bt << 12) | n0) << 6);
        #pragma unroll
        for (int it = 0; it < 16; ++it) {
            int i = (it << 2) + (t >> 6);
            int d = t & 63;
            tile[i * 65 + d] = xr[(i << 6) + d];  // coalesced 256B rows
        }
        __syncthreads();
        unsigned short* dst = vT + (size_t)bt * 262144;
        #pragma unroll
        for (int it = 0; it < 16; ++it) {
            int d = (it << 2) + (t >> 6);
            int n = t & 63;                       // key = n0 + n
            // vT idx: (key>>3)*512 + d*8 + (key&7)
            dst[(((n0 + n) >> 3) << 9) + (d << 3) + (n & 7)]
                = f2bf_bits(tile[n * 65 + d]);
        }
    } else if (b < 7552) {                        // ---- ne_bf ----
        int idx = (b - 6528) * 256 + t;
        ne_bf[idx] = f2bf_bits(node_emb[idx]);
    } else if (b < 7680) {                        // ---- wpT ----
        int ki = b - 7552;
        #pragma unroll
        for (int it = 0; it < 16; ++it) {
            int d = (it << 2) + (t >> 6);
            int o = t & 63;
            tile[d * 65 + o] = wp[(d << 13) + (ki << 6) + o];
        }
        __syncthreads();
        #pragma unroll
        for (int j = 0; j < 16; ++j) {
            int idx = (j << 8) + t;
            int o = idx >> 6, d = idx & 63;
            wpT[(((ki << 6) + o) << 6) + d] = f2bf_bits(tile[d * 65 + o]);
        }
    } else {                                      // ---- bias ----
        for (int idx = t; idx < 384; idx += 256) {
            int bt = idx >> 6, o = idx & 63;
            float bsum = 0.f;
            for (int d = 0; d < 64; ++d)
                bsum += time_emb[(bt << 6) + d] * bias_pool[(d << 6) + o];
            biasw[idx] = bsum;
        }
    }
}

// ---------------- k_attn: half-key flash attention -------------------------
// Block = 4 waves, 32 q rows, one key-half (2048 keys); wave w owns keys
// [half*2048 + w*512, +512). Writes unnormalized partial O + partial l.
// All fragment loads lane-contiguous via eT/vT layouts.
__global__ __launch_bounds__(256, 3) void k_attn(const unsigned short* __restrict__ eT,
                                                 const unsigned short* __restrict__ vT,
                                                 float* __restrict__ P0,
                                                 float* __restrict__ P1,
                                                 float* __restrict__ L0,
                                                 float* __restrict__ L1) {
    __shared__ __align__(16) float Obuf[2][32 * 68];   // 17.4 KB merge buffers
    __shared__ float l_s[4][32];
    const int tid  = threadIdx.x;
    const int w    = tid >> 6;
    const int lane = tid & 63;
    const int l32  = lane & 31;
    const int h    = lane >> 5;

    // bid = inner*2 + half; round-6 XCD swizzle on inner (bijective over 768)
    const int bid   = blockIdx.x;
    const int half  = bid & 1;
    const int inner = bid >> 1;
    const int x8    = inner & 7;
    const int g     = (inner >> 3) & 31;
    const int r3    = inner >> 8;
    const int combo = x8 * 3 + r3;               // 0..23
    const int bt    = combo >> 2;
    const int qbase = ((((combo & 3) << 5) + g) << 5);

    const unsigned short* eb = eT + (size_t)bt * 262144;
    const unsigned short* vb = vT + (size_t)bt * 262144;
    float* Pout = half ? P1 : P0;
    float* Lout = half ? L1 : L0;

    // Q as B-operand: lane n=l32=q, k=h*8+j, d=c*16+h*8+j; scaled by log2e.
    const unsigned short* qp = eb + ((qbase >> 5) << 11) + (h << 8) + (l32 << 3);
    bf16x8 qf[4];
    #pragma unroll
    for (int c = 0; c < 4; ++c) {
        bf16x8 q = *(const bf16x8*)(qp + (c << 9));
        #pragma unroll
        for (int j = 0; j < 8; ++j) q[j] = (__bf16)((float)q[j] * 1.44269504f);
        qf[c] = q;
    }

    f32x16 O0 = zero16(), O1 = zero16();
    float ls = 0.f;

    const int kstart = (half << 11) + (w << 9);  // 512 keys per wave
    const unsigned short* krBase = eb + ((kstart >> 5) << 11) + (h << 8) + (l32 << 3);
    const unsigned short* vrBase = vb + ((kstart >> 3) << 9) + (h << 9) + (l32 << 3);

    bf16x8 kA0, kA1, kA2, kA3, vA0, vA1, vA2, vA3;
    bf16x8 kB0, kB1, kB2, kB3, vB0, vB1, vB2, vB3;

#define LOAD_GRP(gi, K0, K1, K2, K3, V0, V1, V2, V3)                    \
    {                                                                   \
        const unsigned short* kp = krBase + ((gi) << 11);               \
        const unsigned short* vp = vrBase + ((gi) << 11);               \
        K0 = *(const bf16x8*)(kp);                                      \
        K1 = *(const bf16x8*)(kp + 512);                                \
        K2 = *(const bf16x8*)(kp + 1024);                               \
        K3 = *(const bf16x8*)(kp + 1536);                               \
        V0 = *(const bf16x8*)(vp);                                      \
        V1 = *(const bf16x8*)(vp + 256);                                \
        V2 = *(const bf16x8*)(vp + 1024);                               \
        V3 = *(const bf16x8*)(vp + 1280);                               \
    }

#define COMPUTE_GRP(K0, K1, K2, K3, V0, V1, V2, V3)                     \
    {                                                                   \
        f32x16 S = zero16();                                            \
        S = mfma32(K0, qf[0], S);                                       \
        S = mfma32(K1, qf[1], S);                                       \
        S = mfma32(K2, qf[2], S);                                       \
        S = mfma32(K3, qf[3], S);                                       \
        float p[16];                                                    \
        _Pragma("unroll")                                               \
        for (int r = 0; r < 16; ++r) { p[r] = exp2f(S[r]); ls += p[r]; }\
        float r0[4], r1[4];                                             \
        _Pragma("unroll")                                               \
        for (int j = 0; j < 4; ++j) {                                   \
            r0[j] = __shfl_xor(h ? p[j]     : p[4 + j],  32);           \
            r1[j] = __shfl_xor(h ? p[8 + j] : p[12 + j], 32);           \
        }                                                               \
        bf16x8 pf0, pf1;                                                \
        _Pragma("unroll")                                               \
        for (int j = 0; j < 4; ++j) {                                   \
            pf0[j]     = (__bf16)(h ? r0[j]     : p[j]);                \
            pf0[4 + j] = (__bf16)(h ? p[4 + j]  : r0[j]);               \
            pf1[j]     = (__bf16)(h ? r1[j]     : p[8 + j]);            \
            pf1[4 + j] = (__bf16)(h ? p[12 + j] : r1[j]);               \
        }                                                               \
        O0 = mfma32(pf0, V0, O0);                                       \
        O1 = mfma32(pf0, V1, O1);                                       \
        O0 = mfma32(pf1, V2, O0);                                       \
        O1 = mfma32(pf1, V3, O1);                                       \
    }

    LOAD_GRP(0, kA0, kA1, kA2, kA3, vA0, vA1, vA2, vA3);
    for (int gi = 0; gi < 14; gi += 2) {
        LOAD_GRP(gi + 1, kB0, kB1, kB2, kB3, vB0, vB1, vB2, vB3);
        COMPUTE_GRP(kA0, kA1, kA2, kA3, vA0, vA1, vA2, vA3);
        LOAD_GRP(gi + 2, kA0, kA1, kA2, kA3, vA0, vA1, vA2, vA3);
        COMPUTE_GRP(kB0, kB1, kB2, kB3, vB0, vB1, vB2, vB3);
    }
    LOAD_GRP(15, kB0, kB1, kB2, kB3, vB0, vB1, vB2, vB3);
    COMPUTE_GRP(kA0, kA1, kA2, kA3, vA0, vA1, vA2, vA3);
    COMPUTE_GRP(kB0, kB1, kB2, kB3, vB0, vB1, vB2, vB3);
#undef LOAD_GRP
#undef COMPUTE_GRP

    // ---- merge: l across h, then O across 4 waves via 2 LDS buffers ----
    float lsum2 = ls + __shfl_xor(ls, 32);
    if (h == 0) l_s[w][l32] = lsum2;
    float* buf = Obuf[w & 1];
    if (w < 2) {
        #pragma unroll
        for (int r = 0; r < 16; ++r) {
            int qrow = (r & 3) + ((r >> 2) << 3) + (h << 2);
            buf[qrow * 68 + l32]      = O0[r];
            buf[qrow * 68 + 32 + l32] = O1[r];
        }
    }
    __syncthreads();
    if (w >= 2) {
        #pragma unroll
        for (int r = 0; r < 16; ++r) {
            int qrow = (r & 3) + ((r >> 2) << 3) + (h << 2);
            buf[qrow * 68 + l32]      += O0[r];
            buf[qrow * 68 + 32 + l32] += O1[r];
        }
    }
    __syncthreads();
    {
        int q  = tid >> 3;
        int d0 = (tid & 7) << 3;
        const float* b0 = Obuf[0] + q * 68 + d0;
        const float* b1 = Obuf[1] + q * 68 + d0;
        float* dst = Pout + (((size_t)(bt << 12) + qbase + q) << 6) + d0;
        #pragma unroll
        for (int i = 0; i < 8; ++i) dst[i] = b0[i] + b1[i];
        if ((tid & 7) == 0)
            Lout[(bt << 12) + qbase + q] =
                l_s[0][q] + l_s[1][q] + l_s[2][q] + l_s[3][q];
    }
}

// ---------------- k_hyper: fused hypernetwork contraction ------------------
// Main loop byte-identical to round-4 (known good); staging merges the two
// attention partials: xg2 = (P0+P1) * 1/(L0+L1).
__global__ __launch_bounds__(256, 2) void k_hyper(const float* __restrict__ x,
                                                  const float* __restrict__ P0,
                                                  const float* __restrict__ P1,
                                                  const float* __restrict__ L0,
                                                  const float* __restrict__ L1,
                                                  const unsigned short* __restrict__ ne_bf,
                                                  const unsigned short* __restrict__ wpT,
                                                  const float* __restrict__ bias_ws,
                                                  float* __restrict__ out) {
    __shared__ float smem[13056];          // 52.2 KB: xg (4x3104) then red (4x3264)
    __shared__ float invl_s[96];
    const int t    = threadIdx.x;
    const int w    = t >> 6;
    const int lane = t & 63;
    const int l16  = lane & 15;
    const int quad = lane >> 4;
    const int n0   = (blockIdx.x >> 1) << 4;
    const int oh   = blockIdx.x & 1;       // o-half

    if (t < 96) {
        int bt = t % 6, nl = t / 6;
        int idx = (bt << 12) + n0 + nl;
        invl_s[t] = 1.f / (L0[idx] + L1[idx]);
    }
    __syncthreads();

    float* xg_s = smem + w * 3104;
    const int i0 = (w & 1) << 5;
    for (int it = 0; it < 48; ++it) {
        int j  = (it << 6) + lane;         // 0..3071
        int kk = j & 31;
        int btnl = j >> 5;                 // 0..95
        int bt = btnl % 6;
        int nl = btnl / 6;
        size_t idx = (((size_t)(bt << 12) + n0 + nl) << 6) + i0 + kk;
        float v;
        if (w < 2) v = x[idx];
        else       v = (P0[idx] + P1[idx]) * invl_s[btnl];
        xg_s[kk * 97 + btnl] = v;
    }
    __syncthreads();

    const unsigned short* nb = ne_bf + ((n0 + l16) << 6) + (quad << 3);
    bf16x8 a0 = *(const bf16x8*)(nb);
    bf16x8 a1 = *(const bf16x8*)(nb + 32);

    float oac[2][4][6];
    #pragma unroll
    for (int oc = 0; oc < 2; ++oc)
        #pragma unroll
        for (int r = 0; r < 4; ++r)
            #pragma unroll
            for (int bt = 0; bt < 6; ++bt) oac[oc][r][bt] = 0.f;

    const int ki_base = w << 5;
    #pragma unroll 2
    for (int kk = 0; kk < 32; ++kk) {
        const int ki = ki_base + kk;
        float g[4][6];
        #pragma unroll
        for (int r = 0; r < 4; ++r) {
            const float* gp = xg_s + kk * 97 + ((quad << 2) + r) * 6;
            #pragma unroll
            for (int bt = 0; bt < 6; ++bt) g[r][bt] = gp[bt];
        }
        #pragma unroll
        for (int oc = 0; oc < 2; ++oc) {
            const unsigned short* bp =
                wpT + (((ki << 6) + ((oh * 2 + oc) << 4) + l16) << 6) + (quad << 3);
            bf16x8 b0 = *(const bf16x8*)(bp);
            bf16x8 b1 = *(const bf16x8*)(bp + 32);
            f32x4 wf = mfma16(a0, b0, f32x4{0.f, 0.f, 0.f, 0.f});
            wf = mfma16(a1, b1, wf);
            #pragma unroll
            for (int r = 0; r < 4; ++r)
                #pragma unroll
                for (int bt = 0; bt < 6; ++bt)
                    oac[oc][r][bt] += wf[r] * g[r][bt];
        }
    }

    __syncthreads();                        // xg_s dead; smem becomes red
    #pragma unroll
    for (int oc = 0; oc < 2; ++oc)
        #pragma unroll
        for (int r = 0; r < 4; ++r)
            #pragma unroll
            for (int bt = 0; bt < 6; ++bt)
                smem[w * 3264 + ((quad << 2) + r) * 204 + bt * 34 + (oc << 4) + l16]
                    = oac[oc][r][bt];
    __syncthreads();
    #pragma unroll
    for (int rr = 0; rr < 4; ++rr) {
        int nl = (w << 2) + rr;
        #pragma unroll
        for (int bp2 = 0; bp2 < 3; ++bp2) {
            int bt = bp2 * 2 + (lane >> 5);
            int ol = lane & 31;
            int o  = (oh << 5) + ol;
            int a  = nl * 204 + bt * 34 + ol;
            float v = smem[a] + smem[a + 3264] + smem[a + 6528] + smem[a + 9792]
                    + bias_ws[(bt << 6) + o];
            out[(((size_t)(bt << 12) + n0 + nl) << 6) + o] = v;
        }
    }
}

// ---------------------------------------------------------------------------
extern "C" void kernel_launch(void* const* d_in, const int* in_sizes, int n_in,
                              void* d_out, int out_size, void* d_ws, size_t ws_size,
                              hipStream_t stream) {
    const float* x         = (const float*)d_in[0];
    const float* node_emb  = (const float*)d_in[1];
    const float* time_emb  = (const float*)d_in[2];
    const float* wp        = (const float*)d_in[3];
    const float* bias_pool = (const float*)d_in[4];
    const float* gamma     = (const float*)d_in[5];
    const float* beta      = (const float*)d_in[6];
    float* out = (float*)d_out;

    char* wsb = (char*)d_ws;
    unsigned short* eT    = (unsigned short*)(wsb);                  // 3 MB
    unsigned short* vT    = (unsigned short*)(wsb + 3145728);        // 3 MB
    float*          P0    = (float*)         (wsb + 6291456);        // 6.3 MB
    float*          P1    = (float*)         (wsb + 12582912);       // 6.3 MB
    unsigned short* wpT   = (unsigned short*)(wsb + 18874368);       // 1 MB
    unsigned short* ne_bf = (unsigned short*)(wsb + 19922944);       // 0.5 MB
    float*          biasw = (float*)         (wsb + 20447232);       // 1.5 KB
    float*          L0    = (float*)         (wsb + 20448768);       // 96 KB
    float*          L1    = (float*)         (wsb + 20547072);       // 96 KB

    k_prep<<<7681, 256, 0, stream>>>(x, node_emb, time_emb, wp, bias_pool,
                                     gamma, beta, eT, vT, ne_bf, wpT, biasw);
    k_attn<<<1536, 256, 0, stream>>>(eT, vT, P0, P1, L0, L1);
    k_hyper<<<512, 256, 0, stream>>>(x, P0, P1, L0, L1, ne_bf, wpT, biasw, out);
}

// Round 12
// 153.037 us; speedup vs baseline: 3.5494x; 1.1249x over previous
//
#include <hip/hip_runtime.h>

// ---------------------------------------------------------------------------
// DSTGCN fused pipeline, MI355X gfx950.
// Round 12 = round 9 (known good, 172us) + ONE change: wp staged in
// frag-linear layout wpB[ki][ot][frag][lane][8] so k_hyper's B-fragment
// loads are lane-contiguous (2 cache lines/instr vs 16) — same TA fix that
// took k_attn out of the top-5 in round 9. k_attn byte-identical to round 9.
// ---------------------------------------------------------------------------

using bf16x8 = __attribute__((ext_vector_type(8))) __bf16;
using f32x4  = __attribute__((ext_vector_type(4))) float;
using f32x16 = __attribute__((ext_vector_type(16))) float;

__device__ __forceinline__ unsigned short f2bf_bits(float f) {
    unsigned int u = __float_as_uint(f);
    u += 0x7fffu + ((u >> 16) & 1u);          // RNE
    return (unsigned short)(u >> 16);
}

__device__ __forceinline__ f32x4 mfma16(bf16x8 a, bf16x8 b, f32x4 c) {
    return __builtin_amdgcn_mfma_f32_16x16x32_bf16(a, b, c, 0, 0, 0);
}
__device__ __forceinline__ f32x16 mfma32(bf16x8 a, bf16x8 b, f32x16 c) {
    return __builtin_amdgcn_mfma_f32_32x32x16_bf16(a, b, c, 0, 0, 0);
}
__device__ __forceinline__ f32x16 zero16() {
    f32x16 z;
    #pragma unroll
    for (int i = 0; i < 16; ++i) z[i] = 0.f;
    return z;
}

// ---------------- k_prep: all preprocessing in one launch ------------------
// [0,6144)    : LN -> eT
// [6144,6528) : x -> vT
// [6528,7552) : ne_bf
// [7552,7680) : wpB[ki][ot][frag][pos][j] = bf16(wp[d][ki][o]),
//               d = frag*32 + (pos>>4)*8 + j, o = ot*16 + (pos&15)
// block 7680  : biasw
__global__ __launch_bounds__(256) void k_prep(const float* __restrict__ x,
                                              const float* __restrict__ node_emb,
                                              const float* __restrict__ time_emb,
                                              const float* __restrict__ wp,
                                              const float* __restrict__ bias_pool,
                                              const float* __restrict__ gamma,
                                              const float* __restrict__ beta,
                                              unsigned short* __restrict__ eT,
                                              unsigned short* __restrict__ vT,
                                              unsigned short* __restrict__ ne_bf,
                                              unsigned short* __restrict__ wpB,
                                              float* __restrict__ biasw) {
    __shared__ float tile[64 * 65];
    const int b = blockIdx.x;
    const int t = threadIdx.x;
    if (b < 6144) {                               // ---- LayerNorm -> eT ----
        int rowf = b * 4 + (t >> 6);              // bt*4096+n
        int d    = t & 63;
        int bt = rowf >> 12, row = rowf & 4095;
        float v = node_emb[(row << 6) | d] + time_emb[(bt << 6) | d];
        float s = v, s2 = v * v;
        #pragma unroll
        for (int off = 32; off; off >>= 1) {
            s  += __shfl_xor(s,  off);
            s2 += __shfl_xor(s2, off);
        }
        float mu  = s * 0.015625f;
        float var = s2 * 0.015625f - mu * mu;
        float r   = rsqrtf(var + 1e-12f);
        float o   = (v - mu) * r * gamma[d] + beta[d];
        size_t idx = (size_t)bt * 262144 + ((row >> 5) << 11) + ((d >> 4) << 9)
                   + (((d >> 3) & 1) << 8) + ((row & 31) << 3) + (d & 7);
        eT[idx] = f2bf_bits(o);
    } else if (b < 6528) {                        // ---- x -> vT ----
        int bb = b - 6144;
        int bt = bb >> 6, n0 = (bb & 63) << 6;
        const float* xr = x + ((size_t)((bt << 12) | n0) << 6);
        #pragma unroll
        for (int it = 0; it < 16; ++it) {
            int i = (it << 2) + (t >> 6);
            int d = t & 63;
            tile[i * 65 + d] = xr[(i << 6) + d];  // coalesced 256B rows
        }
        __syncthreads();
        unsigned short* dst = vT + (size_t)bt * 262144;
        #pragma unroll
        for (int it = 0; it < 16; ++it) {
            int d = (it << 2) + (t >> 6);
            int n = t & 63;                       // key = n0 + n
            dst[(((n0 + n) >> 3) << 9) + (d << 3) + (n & 7)]
                = f2bf_bits(tile[n * 65 + d]);
        }
    } else if (b < 7552) {                        // ---- ne_bf ----
        int idx = (b - 6528) * 256 + t;
        ne_bf[idx] = f2bf_bits(node_emb[idx]);
    } else if (b < 7680) {                        // ---- wpB (frag-linear) ----
        int ki = b - 7552;
        #pragma unroll
        for (int it = 0; it < 16; ++it) {
            int d = (it << 2) + (t >> 6);
            int o = t & 63;
            tile[d * 65 + o] = wp[(d << 13) + (ki << 6) + o];
        }
        __syncthreads();
        unsigned short* dst = wpB + ((size_t)ki << 12);   // 4096 shorts / ki
        #pragma unroll
        for (int it = 0; it < 2; ++it) {
            int u    = (it << 8) + t;             // 0..511
            int ot   = u >> 7;
            int frag = (u >> 6) & 1;
            int pos  = u & 63;
            int quad = pos >> 4, l16 = pos & 15;
            unsigned short* dp = dst + ((((ot << 1) + frag) << 9) + (pos << 3));
            #pragma unroll
            for (int j = 0; j < 8; ++j)
                dp[j] = f2bf_bits(
                    tile[((frag << 5) + (quad << 3) + j) * 65 + (ot << 4) + l16]);
        }
    } else {                                      // ---- bias ----
        for (int idx = t; idx < 384; idx += 256) {
            int bt = idx >> 6, o = idx & 63;
            float bsum = 0.f;
            for (int d = 0; d < 64; ++d)
                bsum += time_emb[(bt << 6) + d] * bias_pool[(d << 6) + o];
            biasw[idx] = bsum;
        }
    }
}

// ---------------- k_attn: half-key flash attention (round-9) ---------------
__global__ __launch_bounds__(256, 3) void k_attn(const unsigned short* __restrict__ eT,
                                                 const unsigned short* __restrict__ vT,
                                                 float* __restrict__ P0,
                                                 float* __restrict__ P1,
                                                 float* __restrict__ L0,
                                                 float* __restrict__ L1) {
    __shared__ __align__(16) float Obuf[2][32 * 68];   // 17.4 KB merge buffers
    __shared__ float l_s[4][32];
    const int tid  = threadIdx.x;
    const int w    = tid >> 6;
    const int lane = tid & 63;
    const int l32  = lane & 31;
    const int h    = lane >> 5;

    const int bid   = blockIdx.x;
    const int half  = bid & 1;
    const int inner = bid >> 1;
    const int x8    = inner & 7;
    const int g     = (inner >> 3) & 31;
    const int r3    = inner >> 8;
    const int combo = x8 * 3 + r3;               // 0..23
    const int bt    = combo >> 2;
    const int qbase = ((((combo & 3) << 5) + g) << 5);

    const unsigned short* eb = eT + (size_t)bt * 262144;
    const unsigned short* vb = vT + (size_t)bt * 262144;
    float* Pout = half ? P1 : P0;
    float* Lout = half ? L1 : L0;

    const unsigned short* qp = eb + ((qbase >> 5) << 11) + (h << 8) + (l32 << 3);
    bf16x8 qf[4];
    #pragma unroll
    for (int c = 0; c < 4; ++c) {
        bf16x8 q = *(const bf16x8*)(qp + (c << 9));
        #pragma unroll
        for (int j = 0; j < 8; ++j) q[j] = (__bf16)((float)q[j] * 1.44269504f);
        qf[c] = q;
    }

    f32x16 O0 = zero16(), O1 = zero16();
    float ls = 0.f;

    const int kstart = (half << 11) + (w << 9);  // 512 keys per wave
    const unsigned short* krBase = eb + ((kstart >> 5) << 11) + (h << 8) + (l32 << 3);
    const unsigned short* vrBase = vb + ((kstart >> 3) << 9) + (h << 9) + (l32 << 3);

    bf16x8 kA0, kA1, kA2, kA3, vA0, vA1, vA2, vA3;
    bf16x8 kB0, kB1, kB2, kB3, vB0, vB1, vB2, vB3;

#define LOAD_GRP(gi, K0, K1, K2, K3, V0, V1, V2, V3)                    \
    {                                                                   \
        const unsigned short* kp = krBase + ((gi) << 11);               \
        const unsigned short* vp = vrBase + ((gi) << 11);               \
        K0 = *(const bf16x8*)(kp);                                      \
        K1 = *(const bf16x8*)(kp + 512);                                \
        K2 = *(const bf16x8*)(kp + 1024);                               \
        K3 = *(const bf16x8*)(kp + 1536);                               \
        V0 = *(const bf16x8*)(vp);                                      \
        V1 = *(const bf16x8*)(vp + 256);                                \
        V2 = *(const bf16x8*)(vp + 1024);                               \
        V3 = *(const bf16x8*)(vp + 1280);                               \
    }

#define COMPUTE_GRP(K0, K1, K2, K3, V0, V1, V2, V3)                     \
    {                                                                   \
        f32x16 S = zero16();                                            \
        S = mfma32(K0, qf[0], S);                                       \
        S = mfma32(K1, qf[1], S);                                       \
        S = mfma32(K2, qf[2], S);                                       \
        S = mfma32(K3, qf[3], S);                                       \
        float p[16];                                                    \
        _Pragma("unroll")                                               \
        for (int r = 0; r < 16; ++r) { p[r] = exp2f(S[r]); ls += p[r]; }\
        float r0[4], r1[4];                                             \
        _Pragma("unroll")                                               \
        for (int j = 0; j < 4; ++j) {                                   \
            r0[j] = __shfl_xor(h ? p[j]     : p[4 + j],  32);           \
            r1[j] = __shfl_xor(h ? p[8 + j] : p[12 + j], 32);           \
        }                                                               \
        bf16x8 pf0, pf1;                                                \
        _Pragma("unroll")                                               \
        for (int j = 0; j < 4; ++j) {                                   \
            pf0[j]     = (__bf16)(h ? r0[j]     : p[j]);                \
            pf0[4 + j] = (__bf16)(h ? p[4 + j]  : r0[j]);               \
            pf1[j]     = (__bf16)(h ? r1[j]     : p[8 + j]);            \
            pf1[4 + j] = (__bf16)(h ? p[12 + j] : r1[j]);               \
        }                                                               \
        O0 = mfma32(pf0, V0, O0);                                       \
        O1 = mfma32(pf0, V1, O1);                                       \
        O0 = mfma32(pf1, V2, O0);                                       \
        O1 = mfma32(pf1, V3, O1);                                       \
    }

    LOAD_GRP(0, kA0, kA1, kA2, kA3, vA0, vA1, vA2, vA3);
    for (int gi = 0; gi < 14; gi += 2) {
        LOAD_GRP(gi + 1, kB0, kB1, kB2, kB3, vB0, vB1, vB2, vB3);
        COMPUTE_GRP(kA0, kA1, kA2, kA3, vA0, vA1, vA2, vA3);
        LOAD_GRP(gi + 2, kA0, kA1, kA2, kA3, vA0, vA1, vA2, vA3);
        COMPUTE_GRP(kB0, kB1, kB2, kB3, vB0, vB1, vB2, vB3);
    }
    LOAD_GRP(15, kB0, kB1, kB2, kB3, vB0, vB1, vB2, vB3);
    COMPUTE_GRP(kA0, kA1, kA2, kA3, vA0, vA1, vA2, vA3);
    COMPUTE_GRP(kB0, kB1, kB2, kB3, vB0, vB1, vB2, vB3);
#undef LOAD_GRP
#undef COMPUTE_GRP

    float lsum2 = ls + __shfl_xor(ls, 32);
    if (h == 0) l_s[w][l32] = lsum2;
    float* buf = Obuf[w & 1];
    if (w < 2) {
        #pragma unroll
        for (int r = 0; r < 16; ++r) {
            int qrow = (r & 3) + ((r >> 2) << 3) + (h << 2);
            buf[qrow * 68 + l32]      = O0[r];
            buf[qrow * 68 + 32 + l32] = O1[r];
        }
    }
    __syncthreads();
    if (w >= 2) {
        #pragma unroll
        for (int r = 0; r < 16; ++r) {
            int qrow = (r & 3) + ((r >> 2) << 3) + (h << 2);
            buf[qrow * 68 + l32]      += O0[r];
            buf[qrow * 68 + 32 + l32] += O1[r];
        }
    }
    __syncthreads();
    {
        int q  = tid >> 3;
        int d0 = (tid & 7) << 3;
        const float* b0 = Obuf[0] + q * 68 + d0;
        const float* b1 = Obuf[1] + q * 68 + d0;
        float* dst = Pout + (((size_t)(bt << 12) + qbase + q) << 6) + d0;
        #pragma unroll
        for (int i = 0; i < 8; ++i) dst[i] = b0[i] + b1[i];
        if ((tid & 7) == 0)
            Lout[(bt << 12) + qbase + q] =
                l_s[0][q] + l_s[1][q] + l_s[2][q] + l_s[3][q];
    }
}

// ---------------- k_hyper: fused hypernetwork contraction ------------------
// Round-9 structure; ONLY the wp B-fragment addressing changed to the
// frag-linear wpB layout (lane-contiguous loads).
__global__ __launch_bounds__(256, 2) void k_hyper(const float* __restrict__ x,
                                                  const float* __restrict__ P0,
                                                  const float* __restrict__ P1,
                                                  const float* __restrict__ L0,
                                                  const float* __restrict__ L1,
                                                  const unsigned short* __restrict__ ne_bf,
                                                  const unsigned short* __restrict__ wpB,
                                                  const float* __restrict__ bias_ws,
                                                  float* __restrict__ out) {
    __shared__ float smem[13056];          // 52.2 KB: xg (4x3104) then red (4x3264)
    __shared__ float invl_s[96];
    const int t    = threadIdx.x;
    const int w    = t >> 6;
    const int lane = t & 63;
    const int l16  = lane & 15;
    const int quad = lane >> 4;
    const int n0   = (blockIdx.x >> 1) << 4;
    const int oh   = blockIdx.x & 1;       // o-half

    if (t < 96) {
        int bt = t % 6, nl = t / 6;
        int idx = (bt << 12) + n0 + nl;
        invl_s[t] = 1.f / (L0[idx] + L1[idx]);
    }
    __syncthreads();

    float* xg_s = smem + w * 3104;
    const int i0 = (w & 1) << 5;
    for (int it = 0; it < 48; ++it) {
        int j  = (it << 6) + lane;         // 0..3071
        int kk = j & 31;
        int btnl = j >> 5;                 // 0..95
        int bt = btnl % 6;
        int nl = btnl / 6;
        size_t idx = (((size_t)(bt << 12) + n0 + nl) << 6) + i0 + kk;
        float v;
        if (w < 2) v = x[idx];
        else       v = (P0[idx] + P1[idx]) * invl_s[btnl];
        xg_s[kk * 97 + btnl] = v;
    }
    __syncthreads();

    const unsigned short* nb = ne_bf + ((n0 + l16) << 6) + (quad << 3);
    bf16x8 a0 = *(const bf16x8*)(nb);
    bf16x8 a1 = *(const bf16x8*)(nb + 32);

    float oac[2][4][6];
    #pragma unroll
    for (int oc = 0; oc < 2; ++oc)
        #pragma unroll
        for (int r = 0; r < 4; ++r)
            #pragma unroll
            for (int bt = 0; bt < 6; ++bt) oac[oc][r][bt] = 0.f;

    const int ki_base = w << 5;
    #pragma unroll 2
    for (int kk = 0; kk < 32; ++kk) {
        const int ki = ki_base + kk;
        float g[4][6];
        #pragma unroll
        for (int r = 0; r < 4; ++r) {
            const float* gp = xg_s + kk * 97 + ((quad << 2) + r) * 6;
            #pragma unroll
            for (int bt = 0; bt < 6; ++bt) g[r][bt] = gp[bt];
        }
        #pragma unroll
        for (int oc = 0; oc < 2; ++oc) {
            // frag-linear: base + lane*8 shorts (2 cache lines per load)
            const unsigned short* bp =
                wpB + ((((size_t)ki << 2) + (oh * 2 + oc)) << 10) + (lane << 3);
            bf16x8 b0 = *(const bf16x8*)(bp);
            bf16x8 b1 = *(const bf16x8*)(bp + 512);
            f32x4 wf = mfma16(a0, b0, f32x4{0.f, 0.f, 0.f, 0.f});
            wf = mfma16(a1, b1, wf);
            #pragma unroll
            for (int r = 0; r < 4; ++r)
                #pragma unroll
                for (int bt = 0; bt < 6; ++bt)
                    oac[oc][r][bt] += wf[r] * g[r][bt];
        }
    }

    __syncthreads();                        // xg_s dead; smem becomes red
    #pragma unroll
    for (int oc = 0; oc < 2; ++oc)
        #pragma unroll
        for (int r = 0; r < 4; ++r)
            #pragma unroll
            for (int bt = 0; bt < 6; ++bt)
                smem[w * 3264 + ((quad << 2) + r) * 204 + bt * 34 + (oc << 4) + l16]
                    = oac[oc][r][bt];
    __syncthreads();
    #pragma unroll
    for (int rr = 0; rr < 4; ++rr) {
        int nl = (w << 2) + rr;
        #pragma unroll
        for (int bp2 = 0; bp2 < 3; ++bp2) {
            int bt = bp2 * 2 + (lane >> 5);
            int ol = lane & 31;
            int o  = (oh << 5) + ol;
            int a  = nl * 204 + bt * 34 + ol;
            float v = smem[a] + smem[a + 3264] + smem[a + 6528] + smem[a + 9792]
                    + bias_ws[(bt << 6) + o];
            out[(((size_t)(bt << 12) + n0 + nl) << 6) + o] = v;
        }
    }
}

// ---------------------------------------------------------------------------
extern "C" void kernel_launch(void* const* d_in, const int* in_sizes, int n_in,
                              void* d_out, int out_size, void* d_ws, size_t ws_size,
                              hipStream_t stream) {
    const float* x         = (const float*)d_in[0];
    const float* node_emb  = (const float*)d_in[1];
    const float* time_emb  = (const float*)d_in[2];
    const float* wp        = (const float*)d_in[3];
    const float* bias_pool = (const float*)d_in[4];
    const float* gamma     = (const float*)d_in[5];
    const float* beta      = (const float*)d_in[6];
    float* out = (float*)d_out;

    char* wsb = (char*)d_ws;
    unsigned short* eT    = (unsigned short*)(wsb);                  // 3 MB
    unsigned short* vT    = (unsigned short*)(wsb + 3145728);        // 3 MB
    float*          P0    = (float*)         (wsb + 6291456);        // 6.3 MB
    float*          P1    = (float*)         (wsb + 12582912);       // 6.3 MB
    unsigned short* wpB   = (unsigned short*)(wsb + 18874368);       // 1 MB
    unsigned short* ne_bf = (unsigned short*)(wsb + 19922944);       // 0.5 MB
    float*          biasw = (float*)         (wsb + 20447232);       // 1.5 KB
    float*          L0    = (float*)         (wsb + 20448768);       // 96 KB
    float*          L1    = (float*)         (wsb + 20547072);       // 96 KB

    k_prep<<<7681, 256, 0, stream>>>(x, node_emb, time_emb, wp, bias_pool,
                                     gamma, beta, eT, vT, ne_bf, wpB, biasw);
    k_attn<<<1536, 256, 0, stream>>>(eT, vT, P0, P1, L0, L1);
    k_hyper<<<512, 256, 0, stream>>>(x, P0, P1, L0, L1, ne_bf, wpB, biasw, out);
}

// Round 13
// 144.587 us; speedup vs baseline: 3.7568x; 1.0584x over previous
//
#include <hip/hip_runtime.h>

// ---------------------------------------------------------------------------
// DSTGCN fused pipeline, MI355X gfx950.
// Round 13 = round 12 + (a) raw v_exp_f32 (__builtin_amdgcn_exp2f — logits
// bounded, no denorm fixup needed), (b) u32-pair P packing (v_perm truncate,
// 4 u32 shuffles instead of 8 float shuffles, no scalar cvts), (c) 4-way ls
// accumulators, (d) k_prep LN batched 4 rows/wave (ILP over shuffle chains).
// k_hyper byte-identical to round 12 (proven).
// ---------------------------------------------------------------------------

using bf16x8 = __attribute__((ext_vector_type(8))) __bf16;
using f32x4  = __attribute__((ext_vector_type(4))) float;
using f32x16 = __attribute__((ext_vector_type(16))) float;
using u32x4  = __attribute__((ext_vector_type(4))) unsigned int;

__device__ __forceinline__ unsigned short f2bf_bits(float f) {
    unsigned int u = __float_as_uint(f);
    u += 0x7fffu + ((u >> 16) & 1u);          // RNE
    return (unsigned short)(u >> 16);
}

// pack two floats' high halves: lo16 = hi16(a), hi16 = hi16(b)  (bf16 trunc)
__device__ __forceinline__ unsigned int PK(float a, float b) {
    return __builtin_amdgcn_perm(__float_as_uint(b), __float_as_uint(a),
                                 0x07060302u);
}

__device__ __forceinline__ f32x4 mfma16(bf16x8 a, bf16x8 b, f32x4 c) {
    return __builtin_amdgcn_mfma_f32_16x16x32_bf16(a, b, c, 0, 0, 0);
}
__device__ __forceinline__ f32x16 mfma32(bf16x8 a, bf16x8 b, f32x16 c) {
    return __builtin_amdgcn_mfma_f32_32x32x16_bf16(a, b, c, 0, 0, 0);
}
__device__ __forceinline__ f32x16 zero16() {
    f32x16 z;
    #pragma unroll
    for (int i = 0; i < 16; ++i) z[i] = 0.f;
    return z;
}

// ---------------- k_prep: all preprocessing in one launch ------------------
// [0,1536)    : LN -> eT (16 rows/block, 4 rows/wave unrolled)
// [1536,1920) : x -> vT
// [1920,2944) : ne_bf
// [2944,3072) : wpB frag-linear
// block 3072  : biasw
__global__ __launch_bounds__(256) void k_prep(const float* __restrict__ x,
                                              const float* __restrict__ node_emb,
                                              const float* __restrict__ time_emb,
                                              const float* __restrict__ wp,
                                              const float* __restrict__ bias_pool,
                                              const float* __restrict__ gamma,
                                              const float* __restrict__ beta,
                                              unsigned short* __restrict__ eT,
                                              unsigned short* __restrict__ vT,
                                              unsigned short* __restrict__ ne_bf,
                                              unsigned short* __restrict__ wpB,
                                              float* __restrict__ biasw) {
    __shared__ float tile[64 * 65];
    const int b = blockIdx.x;
    const int t = threadIdx.x;
    if (b < 1536) {                               // ---- LayerNorm -> eT ----
        int lane = t & 63;
        int row0 = b * 16 + ((t >> 6) << 2);
        float gm = gamma[lane], bb2 = beta[lane];
        #pragma unroll
        for (int ri = 0; ri < 4; ++ri) {
            int rowf = row0 + ri;                 // bt*4096+n
            int bt = rowf >> 12, row = rowf & 4095;
            float v = node_emb[(row << 6) | lane] + time_emb[(bt << 6) | lane];
            float s = v, s2 = v * v;
            #pragma unroll
            for (int off = 32; off; off >>= 1) {
                s  += __shfl_xor(s,  off);
                s2 += __shfl_xor(s2, off);
            }
            float mu  = s * 0.015625f;
            float var = s2 * 0.015625f - mu * mu;
            float r   = rsqrtf(var + 1e-12f);
            float o   = (v - mu) * r * gm + bb2;
            size_t idx = (size_t)bt * 262144 + ((row >> 5) << 11)
                       + ((lane >> 4) << 9) + (((lane >> 3) & 1) << 8)
                       + ((row & 31) << 3) + (lane & 7);
            eT[idx] = f2bf_bits(o);
        }
    } else if (b < 1920) {                        // ---- x -> vT ----
        int bb = b - 1536;
        int bt = bb >> 6, n0 = (bb & 63) << 6;
        const float* xr = x + ((size_t)((bt << 12) | n0) << 6);
        #pragma unroll
        for (int it = 0; it < 16; ++it) {
            int i = (it << 2) + (t >> 6);
            int d = t & 63;
            tile[i * 65 + d] = xr[(i << 6) + d];  // coalesced 256B rows
        }
        __syncthreads();
        unsigned short* dst = vT + (size_t)bt * 262144;
        #pragma unroll
        for (int it = 0; it < 16; ++it) {
            int d = (it << 2) + (t >> 6);
            int n = t & 63;                       // key = n0 + n
            dst[(((n0 + n) >> 3) << 9) + (d << 3) + (n & 7)]
                = f2bf_bits(tile[n * 65 + d]);
        }
    } else if (b < 2944) {                        // ---- ne_bf ----
        int idx = (b - 1920) * 256 + t;
        ne_bf[idx] = f2bf_bits(node_emb[idx]);
    } else if (b < 3072) {                        // ---- wpB (frag-linear) ----
        int ki = b - 2944;
        #pragma unroll
        for (int it = 0; it < 16; ++it) {
            int d = (it << 2) + (t >> 6);
            int o = t & 63;
            tile[d * 65 + o] = wp[(d << 13) + (ki << 6) + o];
        }
        __syncthreads();
        unsigned short* dst = wpB + ((size_t)ki << 12);   // 4096 shorts / ki
        #pragma unroll
        for (int it = 0; it < 2; ++it) {
            int u    = (it << 8) + t;             // 0..511
            int ot   = u >> 7;
            int frag = (u >> 6) & 1;
            int pos  = u & 63;
            int quad = pos >> 4, l16 = pos & 15;
            unsigned short* dp = dst + ((((ot << 1) + frag) << 9) + (pos << 3));
            #pragma unroll
            for (int j = 0; j < 8; ++j)
                dp[j] = f2bf_bits(
                    tile[((frag << 5) + (quad << 3) + j) * 65 + (ot << 4) + l16]);
        }
    } else {                                      // ---- bias ----
        for (int idx = t; idx < 384; idx += 256) {
            int bt = idx >> 6, o = idx & 63;
            float bsum = 0.f;
            for (int d = 0; d < 64; ++d)
                bsum += time_emb[(bt << 6) + d] * bias_pool[(d << 6) + o];
            biasw[idx] = bsum;
        }
    }
}

// ---------------- k_attn: half-key flash attention -------------------------
// Block = 4 waves, 32 q rows, one key-half (2048 keys); wave w owns keys
// [half*2048 + w*512, +512). Raw v_exp softmax (logits bounded by LN),
// u32-pair pack + 4 u32 half-exchanges for the PV A-fragments.
__global__ __launch_bounds__(256, 3) void k_attn(const unsigned short* __restrict__ eT,
                                                 const unsigned short* __restrict__ vT,
                                                 float* __restrict__ P0,
                                                 float* __restrict__ P1,
                                                 float* __restrict__ L0,
                                                 float* __restrict__ L1) {
    __shared__ __align__(16) float Obuf[2][32 * 68];   // 17.4 KB merge buffers
    __shared__ float l_s[4][32];
    const int tid  = threadIdx.x;
    const int w    = tid >> 6;
    const int lane = tid & 63;
    const int l32  = lane & 31;
    const int h    = lane >> 5;

    const int bid   = blockIdx.x;
    const int half  = bid & 1;
    const int inner = bid >> 1;
    const int x8    = inner & 7;
    const int g     = (inner >> 3) & 31;
    const int r3    = inner >> 8;
    const int combo = x8 * 3 + r3;               // 0..23
    const int bt    = combo >> 2;
    const int qbase = ((((combo & 3) << 5) + g) << 5);

    const unsigned short* eb = eT + (size_t)bt * 262144;
    const unsigned short* vb = vT + (size_t)bt * 262144;
    float* Pout = half ? P1 : P0;
    float* Lout = half ? L1 : L0;

    const unsigned short* qp = eb + ((qbase >> 5) << 11) + (h << 8) + (l32 << 3);
    bf16x8 qf[4];
    #pragma unroll
    for (int c = 0; c < 4; ++c) {
        bf16x8 q = *(const bf16x8*)(qp + (c << 9));
        #pragma unroll
        for (int j = 0; j < 8; ++j) q[j] = (__bf16)((float)q[j] * 1.44269504f);
        qf[c] = q;
    }

    f32x16 O0 = zero16(), O1 = zero16();
    float lsa[4] = {0.f, 0.f, 0.f, 0.f};

    const int kstart = (half << 11) + (w << 9);  // 512 keys per wave
    const unsigned short* krBase = eb + ((kstart >> 5) << 11) + (h << 8) + (l32 << 3);
    const unsigned short* vrBase = vb + ((kstart >> 3) << 9) + (h << 9) + (l32 << 3);

    bf16x8 kA0, kA1, kA2, kA3, vA0, vA1, vA2, vA3;
    bf16x8 kB0, kB1, kB2, kB3, vB0, vB1, vB2, vB3;

#define LOAD_GRP(gi, K0, K1, K2, K3, V0, V1, V2, V3)                    \
    {                                                                   \
        const unsigned short* kp = krBase + ((gi) << 11);               \
        const unsigned short* vp = vrBase + ((gi) << 11);               \
        K0 = *(const bf16x8*)(kp);                                      \
        K1 = *(const bf16x8*)(kp + 512);                                \
        K2 = *(const bf16x8*)(kp + 1024);                               \
        K3 = *(const bf16x8*)(kp + 1536);                               \
        V0 = *(const bf16x8*)(vp);                                      \
        V1 = *(const bf16x8*)(vp + 256);                                \
        V2 = *(const bf16x8*)(vp + 1024);                               \
        V3 = *(const bf16x8*)(vp + 1280);                               \
    }

#define COMPUTE_GRP(K0, K1, K2, K3, V0, V1, V2, V3)                     \
    {                                                                   \
        f32x16 S = zero16();                                            \
        S = mfma32(K0, qf[0], S);                                       \
        S = mfma32(K1, qf[1], S);                                       \
        S = mfma32(K2, qf[2], S);                                       \
        S = mfma32(K3, qf[3], S);                                       \
        float p[16];                                                    \
        _Pragma("unroll")                                               \
        for (int r = 0; r < 16; ++r) p[r] = __builtin_amdgcn_exp2f(S[r]); \
        _Pragma("unroll")                                               \
        for (int r = 0; r < 4; ++r)                                     \
            lsa[r] += (p[r] + p[r + 4]) + (p[r + 8] + p[r + 12]);       \
        unsigned int Pa = PK(p[0], p[1]),   Pb = PK(p[2], p[3]);        \
        unsigned int Pc = PK(p[4], p[5]),   Pd = PK(p[6], p[7]);        \
        unsigned int Pe = PK(p[8], p[9]),   Pf = PK(p[10], p[11]);      \
        unsigned int Pg = PK(p[12], p[13]), Ph = PK(p[14], p[15]);      \
        unsigned int e0 = (unsigned int)__shfl_xor((int)(h ? Pa : Pc), 32); \
        unsigned int e1 = (unsigned int)__shfl_xor((int)(h ? Pb : Pd), 32); \
        unsigned int e2 = (unsigned int)__shfl_xor((int)(h ? Pe : Pg), 32); \
        unsigned int e3 = (unsigned int)__shfl_xor((int)(h ? Pf : Ph), 32); \
        u32x4 w0 = { h ? e0 : Pa, h ? e1 : Pb,                          \
                     h ? Pc : e0, h ? Pd : e1 };                        \
        u32x4 w1 = { h ? e2 : Pe, h ? e3 : Pf,                          \
                     h ? Pg : e2, h ? Ph : e3 };                        \
        bf16x8 pf0 = __builtin_bit_cast(bf16x8, w0);                    \
        bf16x8 pf1 = __builtin_bit_cast(bf16x8, w1);                    \
        O0 = mfma32(pf0, V0, O0);                                       \
        O1 = mfma32(pf0, V1, O1);                                       \
        O0 = mfma32(pf1, V2, O0);                                       \
        O1 = mfma32(pf1, V3, O1);                                       \
    }

    LOAD_GRP(0, kA0, kA1, kA2, kA3, vA0, vA1, vA2, vA3);
    for (int gi = 0; gi < 14; gi += 2) {
        LOAD_GRP(gi + 1, kB0, kB1, kB2, kB3, vB0, vB1, vB2, vB3);
        COMPUTE_GRP(kA0, kA1, kA2, kA3, vA0, vA1, vA2, vA3);
        LOAD_GRP(gi + 2, kA0, kA1, kA2, kA3, vA0, vA1, vA2, vA3);
        COMPUTE_GRP(kB0, kB1, kB2, kB3, vB0, vB1, vB2, vB3);
    }
    LOAD_GRP(15, kB0, kB1, kB2, kB3, vB0, vB1, vB2, vB3);
    COMPUTE_GRP(kA0, kA1, kA2, kA3, vA0, vA1, vA2, vA3);
    COMPUTE_GRP(kB0, kB1, kB2, kB3, vB0, vB1, vB2, vB3);
#undef LOAD_GRP
#undef COMPUTE_GRP

    float ls = (lsa[0] + lsa[1]) + (lsa[2] + lsa[3]);
    float lsum2 = ls + __shfl_xor(ls, 32);
    if (h == 0) l_s[w][l32] = lsum2;
    float* buf = Obuf[w & 1];
    if (w < 2) {
        #pragma unroll
        for (int r = 0; r < 16; ++r) {
            int qrow = (r & 3) + ((r >> 2) << 3) + (h << 2);
            buf[qrow * 68 + l32]      = O0[r];
            buf[qrow * 68 + 32 + l32] = O1[r];
        }
    }
    __syncthreads();
    if (w >= 2) {
        #pragma unroll
        for (int r = 0; r < 16; ++r) {
            int qrow = (r & 3) + ((r >> 2) << 3) + (h << 2);
            buf[qrow * 68 + l32]      += O0[r];
            buf[qrow * 68 + 32 + l32] += O1[r];
        }
    }
    __syncthreads();
    {
        int q  = tid >> 3;
        int d0 = (tid & 7) << 3;
        const float* b0 = Obuf[0] + q * 68 + d0;
        const float* b1 = Obuf[1] + q * 68 + d0;
        float* dst = Pout + (((size_t)(bt << 12) + qbase + q) << 6) + d0;
        #pragma unroll
        for (int i = 0; i < 8; ++i) dst[i] = b0[i] + b1[i];
        if ((tid & 7) == 0)
            Lout[(bt << 12) + qbase + q] =
                l_s[0][q] + l_s[1][q] + l_s[2][q] + l_s[3][q];
    }
}

// ---------------- k_hyper: fused hypernetwork contraction (round-12) -------
__global__ __launch_bounds__(256, 2) void k_hyper(const float* __restrict__ x,
                                                  const float* __restrict__ P0,
                                                  const float* __restrict__ P1,
                                                  const float* __restrict__ L0,
                                                  const float* __restrict__ L1,
                                                  const unsigned short* __restrict__ ne_bf,
                                                  const unsigned short* __restrict__ wpB,
                                                  const float* __restrict__ bias_ws,
                                                  float* __restrict__ out) {
    __shared__ float smem[13056];          // 52.2 KB: xg (4x3104) then red (4x3264)
    __shared__ float invl_s[96];
    const int t    = threadIdx.x;
    const int w    = t >> 6;
    const int lane = t & 63;
    const int l16  = lane & 15;
    const int quad = lane >> 4;
    const int n0   = (blockIdx.x >> 1) << 4;
    const int oh   = blockIdx.x & 1;       // o-half

    if (t < 96) {
        int bt = t % 6, nl = t / 6;
        int idx = (bt << 12) + n0 + nl;
        invl_s[t] = 1.f / (L0[idx] + L1[idx]);
    }
    __syncthreads();

    float* xg_s = smem + w * 3104;
    const int i0 = (w & 1) << 5;
    for (int it = 0; it < 48; ++it) {
        int j  = (it << 6) + lane;         // 0..3071
        int kk = j & 31;
        int btnl = j >> 5;                 // 0..95
        int bt = btnl % 6;
        int nl = btnl / 6;
        size_t idx = (((size_t)(bt << 12) + n0 + nl) << 6) + i0 + kk;
        float v;
        if (w < 2) v = x[idx];
        else       v = (P0[idx] + P1[idx]) * invl_s[btnl];
        xg_s[kk * 97 + btnl] = v;
    }
    __syncthreads();

    const unsigned short* nb = ne_bf + ((n0 + l16) << 6) + (quad << 3);
    bf16x8 a0 = *(const bf16x8*)(nb);
    bf16x8 a1 = *(const bf16x8*)(nb + 32);

    float oac[2][4][6];
    #pragma unroll
    for (int oc = 0; oc < 2; ++oc)
        #pragma unroll
        for (int r = 0; r < 4; ++r)
            #pragma unroll
            for (int bt = 0; bt < 6; ++bt) oac[oc][r][bt] = 0.f;

    const int ki_base = w << 5;
    #pragma unroll 2
    for (int kk = 0; kk < 32; ++kk) {
        const int ki = ki_base + kk;
        float g[4][6];
        #pragma unroll
        for (int r = 0; r < 4; ++r) {
            const float* gp = xg_s + kk * 97 + ((quad << 2) + r) * 6;
            #pragma unroll
            for (int bt = 0; bt < 6; ++bt) g[r][bt] = gp[bt];
        }
        #pragma unroll
        for (int oc = 0; oc < 2; ++oc) {
            const unsigned short* bp =
                wpB + ((((size_t)ki << 2) + (oh * 2 + oc)) << 10) + (lane << 3);
            bf16x8 b0 = *(const bf16x8*)(bp);
            bf16x8 b1 = *(const bf16x8*)(bp + 512);
            f32x4 wf = mfma16(a0, b0, f32x4{0.f, 0.f, 0.f, 0.f});
            wf = mfma16(a1, b1, wf);
            #pragma unroll
            for (int r = 0; r < 4; ++r)
                #pragma unroll
                for (int bt = 0; bt < 6; ++bt)
                    oac[oc][r][bt] += wf[r] * g[r][bt];
        }
    }

    __syncthreads();                        // xg_s dead; smem becomes red
    #pragma unroll
    for (int oc = 0; oc < 2; ++oc)
        #pragma unroll
        for (int r = 0; r < 4; ++r)
            #pragma unroll
            for (int bt = 0; bt < 6; ++bt)
                smem[w * 3264 + ((quad << 2) + r) * 204 + bt * 34 + (oc << 4) + l16]
                    = oac[oc][r][bt];
    __syncthreads();
    #pragma unroll
    for (int rr = 0; rr < 4; ++rr) {
        int nl = (w << 2) + rr;
        #pragma unroll
        for (int bp2 = 0; bp2 < 3; ++bp2) {
            int bt = bp2 * 2 + (lane >> 5);
            int ol = lane & 31;
            int o  = (oh << 5) + ol;
            int a  = nl * 204 + bt * 34 + ol;
            float v = smem[a] + smem[a + 3264] + smem[a + 6528] + smem[a + 9792]
                    + bias_ws[(bt << 6) + o];
            out[(((size_t)(bt << 12) + n0 + nl) << 6) + o] = v;
        }
    }
}

// ---------------------------------------------------------------------------
extern "C" void kernel_launch(void* const* d_in, const int* in_sizes, int n_in,
                              void* d_out, int out_size, void* d_ws, size_t ws_size,
                              hipStream_t stream) {
    const float* x         = (const float*)d_in[0];
    const float* node_emb  = (const float*)d_in[1];
    const float* time_emb  = (const float*)d_in[2];
    const float* wp        = (const float*)d_in[3];
    const float* bias_pool = (const float*)d_in[4];
    const float* gamma     = (const float*)d_in[5];
    const float* beta      = (const float*)d_in[6];
    float* out = (float*)d_out;

    char* wsb = (char*)d_ws;
    unsigned short* eT    = (unsigned short*)(wsb);                  // 3 MB
    unsigned short* vT    = (unsigned short*)(wsb + 3145728);        // 3 MB
    float*          P0    = (float*)         (wsb + 6291456);        // 6.3 MB
    float*          P1    = (float*)         (wsb + 12582912);       // 6.3 MB
    unsigned short* wpB   = (unsigned short*)(wsb + 18874368);       // 1 MB
    unsigned short* ne_bf = (unsigned short*)(wsb + 19922944);       // 0.5 MB
    float*          biasw = (float*)         (wsb + 20447232);       // 1.5 KB
    float*          L0    = (float*)         (wsb + 20448768);       // 96 KB
    float*          L1    = (float*)         (wsb + 20547072);       // 96 KB

    k_prep<<<3073, 256, 0, stream>>>(x, node_emb, time_emb, wp, bias_pool,
                                     gamma, beta, eT, vT, ne_bf, wpB, biasw);
    k_attn<<<1536, 256, 0, stream>>>(eT, vT, P0, P1, L0, L1);
    k_hyper<<<512, 256, 0, stream>>>(x, P0, P1, L0, L1, ne_bf, wpB, biasw, out);
}